// Round 5
// baseline (73.249 us; speedup 1.0000x reference)
//
#include <hip/hip_runtime.h>
#include <hip/hip_bf16.h>
#include <math.h>

// Problem constants:
//   feature_map [B=2, H=38, W=38, C=512] float32 (NHWC, C contiguous)
//   rois        [B=2, N=64, 4] int32  (y, x, h, w), h,w >= P
//   out         [B, N, P, P, C] float32, P = 7
#define RB 2
#define RN 64
#define RH 38
#define RW 38
#define RC 512
#define RP 7
#define CELLS (RB * RN * RP * RP)  // 6272
#define CPI (RN * RP * RP)         // cells per image = 3136
#define PPI (CPI / 2)              // cell-pairs per image = 1568
#define C4 (RC / 4)                // 128 float4 per pixel
#define NPIX (RB * RH * RW)        // 2888 pixels
#define STRIPS 5                   // ceil(38/8) strips per row
#define SLEN 8

typedef float vfloat4 __attribute__((ext_vector_type(4)));

__device__ __forceinline__ float4 max4(float4 a, float4 b) {
  return make_float4(fmaxf(a.x, b.x), fmaxf(a.y, b.y), fmaxf(a.z, b.z),
                     fmaxf(a.w, b.w));
}

// Phase 1: Mhv[b][y][x][c] = max over fm[y..y+1][x..x+1] (clamped at edges;
// clamped entries are never read by phase 2). One wave per (b, y, x-strip),
// rolling column-pair so each fm column is loaded once per strip (+1 halo).
__global__ __launch_bounds__(128) void pyr_kernel(
    const float* __restrict__ fm, float* __restrict__ mhv) {
  int sb = blockIdx.x;               // [0, RB*RH*STRIPS)
  int st = sb % STRIPS;
  int t = sb / STRIPS;
  int y = t % RH;
  int b = t / RH;
  int x0 = st * SLEN;
  int len = min(SLEN, RW - x0);      // 8 or 6
  int y1 = min(y + 1, RH - 1);
  int lane = threadIdx.x;            // 0..127 = c4

  const float4* f = (const float4*)fm;
  const float4* r0 = f + ((size_t)((b * RH + y) * RW + x0)) * C4 + lane;
  const float4* r1 = f + ((size_t)((b * RH + y1) * RW + x0)) * C4 + lane;
  float4* o = (float4*)mhv + ((size_t)((b * RH + y) * RW + x0)) * C4 + lane;

  float4 vprev = max4(r0[0], r1[0]);
  for (int dx = 1; dx <= len; ++dx) {
    int col = min(x0 + dx, RW - 1);  // clamp only matters at image edge
    size_t off = (size_t)(col - x0) * C4;
    float4 v = max4(r0[off], r1[off]);
    o[(size_t)(dx - 1) * C4] = max4(vprev, v);
    vprev = v;
  }
}

// Phase 2: one wave per cell, 64 lanes x 8 ch (2x float4). Bins with both
// dims >= 2 are covered by ceil(bh/2)*ceil(bw/2) overlapping 2x2 windows of
// Mhv kept inside the bin (max idempotent -> overlap exact); unit-dim bins
// read fm directly. Cuts main-pass reads ~3x (132 MB -> ~48 MB).
__global__ __launch_bounds__(128) void roi_pool_kernel(
    const float* __restrict__ fm, const float* __restrict__ mhv,
    const int* __restrict__ rois, float* __restrict__ out) {
  int wave = threadIdx.x >> 6;
  int lane = threadIdx.x & 63;

  int bx = blockIdx.x;           // [0, 3136)
  int x = bx & 7;                // presumed XCD (round-robin blockIdx%8)
  int j = bx >> 3;
  int img = x >> 2;
  int pair = img * PPI + ((j << 2) | (x & 3));  // bijective -> [0, 3136)
  int cell = pair * 2 + wave;    // layout ((b*RN+n)*RP+py)*RP+px

  int px = cell % RP;
  int t = cell / RP;
  int py = t % RP;
  t /= RP;                       // roi id
  int b = t / RN;

  const int* r = rois + (t << 2);
  int y0 = __builtin_amdgcn_readfirstlane(r[0]);
  int x0 = __builtin_amdgcn_readfirstlane(r[1]);
  int h = __builtin_amdgcn_readfirstlane(r[2]);
  int w = __builtin_amdgcn_readfirstlane(r[3]);

  int ys = (py * h) / RP, ye = ((py + 1) * h) / RP;
  int xs = (px * w) / RP, xe = ((px + 1) * w) / RP;
  int bh = ye - ys, bw = xe - xs;  // 1..6 each

  float4 m0 = make_float4(-INFINITY, -INFINITY, -INFINITY, -INFINITY);
  float4 m1 = m0;

  if (bh >= 2 && bw >= 2) {
    int ny = (bh + 1) >> 1, nx = (bw + 1) >> 1;  // <= 3 each
    for (int iy = 0; iy < ny; ++iy) {
      int yy = min(ys + 2 * iy, ye - 2);         // window top, inside bin
      const float4* rowp = (const float4*)mhv +
                           ((size_t)((b * RH + y0 + yy) * RW + x0)) * C4 +
                           lane;
      for (int ix = 0; ix < nx; ++ix) {
        int xx = min(xs + 2 * ix, xe - 2);       // window left, inside bin
        const float4* p = rowp + (size_t)xx * C4;
        float4 v0 = p[0];
        float4 v1 = p[64];
        m0 = max4(m0, v0);
        m1 = max4(m1, v1);
      }
    }
  } else {
    for (int yy = ys; yy < ye; ++yy) {
      const float4* rowp = (const float4*)fm +
                           ((size_t)((b * RH + y0 + yy) * RW + x0 + xs)) * C4 +
                           lane;
      for (int xx = 0; xx < bw; ++xx) {
        float4 v0 = rowp[0];
        float4 v1 = rowp[64];
        m0 = max4(m0, v0);
        m1 = max4(m1, v1);
        rowp += C4;
      }
    }
  }

  vfloat4* o = (vfloat4*)(out + (size_t)cell * RC) + lane;
  vfloat4 s0 = {m0.x, m0.y, m0.z, m0.w};
  vfloat4 s1 = {m1.x, m1.y, m1.z, m1.w};
  __builtin_nontemporal_store(s0, o);       // streaming: keep caches for fm
  __builtin_nontemporal_store(s1, o + 64);
}

extern "C" void kernel_launch(void* const* d_in, const int* in_sizes, int n_in,
                              void* d_out, int out_size, void* d_ws, size_t ws_size,
                              hipStream_t stream) {
  const float* fm = (const float*)d_in[0];
  const int* rois = (const int*)d_in[1];
  float* out = (float*)d_out;
  float* mhv = (float*)d_ws;  // 5.92 MB of the 256 MB workspace

  pyr_kernel<<<RB * RH * STRIPS, 128, 0, stream>>>(fm, mhv);
  roi_pool_kernel<<<CELLS / 2, 128, 0, stream>>>(fm, mhv, rois, out);
}

// Round 6
// 68.808 us; speedup vs baseline: 1.0645x; 1.0645x over previous
//
#include <hip/hip_runtime.h>
#include <hip/hip_bf16.h>
#include <math.h>

// Problem constants:
//   feature_map [B=2, H=38, W=38, C=512] float32 (NHWC, C contiguous)
//   rois        [B=2, N=64, 4] int32  (y, x, h, w), h,w >= P
//   out         [B, N, P, P, C] float32, P = 7
#define RB 2
#define RN 64
#define RH 38
#define RW 38
#define RC 512
#define RP 7
#define CELLS (RB * RN * RP * RP)  // 6272
#define CPI (RN * RP * RP)         // cells per image = 3136
#define PPI (CPI / 2)              // cell-pairs per image = 1568

__device__ __forceinline__ float4 max4(float4 a, float4 b) {
  return make_float4(fmaxf(a.x, b.x), fmaxf(a.y, b.y), fmaxf(a.z, b.z),
                     fmaxf(a.w, b.w));
}

// One WAVE per (cell, channel-half): 64 lanes x 4 ch (1x float4) = 256 ch.
// 256-thread blocks -> 3136 blocks. Depth-4 software pipeline (4 loads in
// flight). ROI record fetched through the scalar path (index forced uniform
// via readfirstlane -> s_load_dwordx4) so bin math is scalar and the wave's
// roi->address dependency head is as short as possible.
//
// XCD swizzle (round-robin blockIdx%8 -> XCD assumed): image 0 -> XCDs 0-3,
// image 1 -> XCDs 4-7; each ~3 MB image fits a 4 MB per-XCD L2.
__global__ __launch_bounds__(256) void roi_pool_kernel(
    const float* __restrict__ fm, const int* __restrict__ rois,
    float* __restrict__ out) {
  int wv = threadIdx.x >> 6;     // 0..3
  int lane = threadIdx.x & 63;
  int half = wv & 1;             // channel half: 0 -> ch[0,256), 1 -> [256,512)

  int bx = blockIdx.x;           // [0, 3136)
  int x = bx & 7;                // presumed XCD
  int j = bx >> 3;               // [0, 392)
  int img = x >> 2;              // 0..1
  int pair = img * PPI + ((j << 2) | (x & 3));  // bijective -> [0, 3136)
  int cell = pair * 2 + (wv >> 1);  // [0, 6272)

  int px = cell % RP;
  int t = cell / RP;
  int py = t % RP;
  t /= RP;                       // roi id = b*RN + n
  int b = t / RN;

  // Scalar-path roi fetch: uniform index -> SMEM load, scalar bin math.
  int rid = __builtin_amdgcn_readfirstlane(t);
  const int4 rv = *(const int4*)(rois + (rid << 2));
  int y0 = rv.x, x0 = rv.y, h = rv.z, w = rv.w;

  // Bin [ys,ye) x [xs,xe); bins partition the ROI exactly (h,w >= 7).
  int ys = (py * h) / RP, ye = ((py + 1) * h) / RP;
  int xs = (px * w) / RP, xe = ((px + 1) * w) / RP;
  int bw = xe - xs;
  int cnt = bw * (ye - ys);      // 1..36

  const float4* p =
      (const float4*)(fm +
                      (size_t)((b * RH + y0 + ys) * RW + x0 + xs) * RC) +
      (half << 6) + lane;
  const int pixstep = RC / 4;                  // 128 float4 per pixel
  const int wrapstep = (RW - bw) * (RC / 4);   // extra step at row wrap

#define STEP() \
  { p += pixstep; if (--xrem == 0) { xrem = bw; p += wrapstep; } }

  float4 m = make_float4(-INFINITY, -INFINITY, -INFINITY, -INFINITY);
  int xrem = bw;

  // Depth-4 pipeline. All branches wave-uniform (cnt/bw uniform per wave).
  float4 a0, a1, a2, a3;
  a0 = *p;
  if (cnt > 1) { STEP(); a1 = *p; }
  if (cnt > 2) { STEP(); a2 = *p; }
  if (cnt > 3) { STEP(); a3 = *p; }
  int rem = cnt - 4;
  while (rem > 0) {
    m = max4(m, a0);
    STEP(); a0 = *p; --rem;
    if (rem > 0) {
      m = max4(m, a1);
      STEP(); a1 = *p; --rem;
    }
    if (rem > 0) {
      m = max4(m, a2);
      STEP(); a2 = *p; --rem;
    }
    if (rem > 0) {
      m = max4(m, a3);
      STEP(); a3 = *p; --rem;
    }
  }
  m = max4(m, a0);
  if (cnt > 1) m = max4(m, a1);
  if (cnt > 2) m = max4(m, a2);
  if (cnt > 3) m = max4(m, a3);
#undef STEP

  // Normal (L2-cached) store: out is ~1.6 MB/XCD, L2 absorbs it faster than
  // NT writes pushed toward HBM.
  float4* o = (float4*)(out + (size_t)cell * RC) + (half << 6) + lane;
  *o = m;
}

extern "C" void kernel_launch(void* const* d_in, const int* in_sizes, int n_in,
                              void* d_out, int out_size, void* d_ws, size_t ws_size,
                              hipStream_t stream) {
  const float* fm = (const float*)d_in[0];
  const int* rois = (const int*)d_in[1];
  float* out = (float*)d_out;

  roi_pool_kernel<<<CELLS / 2, 256, 0, stream>>>(fm, rois, out);
}